// Round 11
// baseline (520.075 us; speedup 1.0000x reference)
//
#include <hip/hip_runtime.h>
#include <stdint.h>

#define N_NODES 2048
#define DIM 1024
#define BATCH 16384
#define NEDGE 65536
#define CAP 96
#define NC 256      // compute crew blocks
#define NCOPY 256   // copy crew blocks

typedef __bf16 bf16x8 __attribute__((ext_vector_type(8)));
typedef float f32x4 __attribute__((ext_vector_type(4)));
typedef unsigned short u16;
typedef unsigned int u32;

__device__ __forceinline__ float bf2f(u16 u) {
  union { u32 i; float f; } v; v.i = ((u32)u) << 16; return v.f;
}
__device__ __forceinline__ u16 f2bf(float f) {
  union { float f; u32 i; } v; v.f = f;
  u32 r = v.i + 0x7fffu + ((v.i >> 16) & 1u);
  return (u16)(r >> 16);
}

// ---------- feat->out copy: 32 rows per task (slots 2..6) ----------
__device__ __forceinline__ void copy_feat_rows(const float* __restrict__ feat,
                                               float* __restrict__ out,
                                               int row0, int tid) {
  #pragma unroll 4
  for (int t = row0; t < row0 + 32; ++t) {
    int b = t / 5, s = t - b * 5 + 2;
    size_t o = ((size_t)b * 7 + s) * DIM + tid * 4;
    f32x4 v = __builtin_nontemporal_load((const f32x4*)(feat + o));
    __builtin_nontemporal_store(v, (f32x4*)(out + o));
  }
}

// ---------- bucket fill; detects int64-vs-int32 inline ----------
__global__ __launch_bounds__(256) void k_bucket(const int* __restrict__ dx,
                                                int* __restrict__ flag,
                                                int* __restrict__ counts,
                                                int* __restrict__ bucket) {
  int is64 = 1;
  for (int j = 0; j < 32; ++j)
    if (dx[2 * j + 1] != 0) { is64 = 0; break; }
  if (blockIdx.x == 0 && threadIdx.x == 0) *flag = is64;
  int i = blockIdx.x * 256 + threadIdx.x;
  if (i >= 2 * BATCH) return;
  long p = (i < BATCH) ? 7L * i : 7L * (i - BATCH) + 1;
  int n = dx[is64 ? 2 * p : p] & (N_NODES - 1);
  int slot = atomicAdd(&counts[n], 1);
  if (slot < CAP) bucket[n * CAP + slot] = i;
}

// ---------- merged: nodesum (2048) | rowptr (9) | transpose3 (8192) ----------
__global__ __launch_bounds__(256) void k_prep2(const float* __restrict__ feat,
                                               const int* __restrict__ counts,
                                               const int* __restrict__ bucket,
                                               u16* __restrict__ A1,
                                               const int* __restrict__ adj_rows,
                                               int* __restrict__ row_ptr,
                                               const float* __restrict__ W1,
                                               const float* __restrict__ W2,
                                               const float* __restrict__ W3,
                                               u16* __restrict__ Wt1,
                                               u16* __restrict__ Wt2,
                                               u16* __restrict__ Wt3) {
  __shared__ __align__(16) u16 t[32][33];
  int bid = blockIdx.x;
  int tid = threadIdx.x;
  if (bid < 2048) {
    int n = bid;
    int cnt = counts[n]; if (cnt > CAP) cnt = CAP;
    float a0 = 0.f, a1 = 0.f, a2 = 0.f, a3 = 0.f;
    for (int j = 0; j < cnt; ++j) {
      int i = bucket[n * CAP + j];
      size_t rowoff = (i < BATCH) ? ((size_t)i * 7) * DIM
                                  : ((size_t)(i - BATCH) * 7 + 1) * DIM;
      f32x4 v = *(const f32x4*)(feat + rowoff + tid * 4);
      a0 += v[0]; a1 += v[1]; a2 += v[2]; a3 += v[3];
    }
    ushort4 o; o.x = f2bf(a0); o.y = f2bf(a1); o.z = f2bf(a2); o.w = f2bf(a3);
    *(ushort4*)(A1 + (size_t)n * DIM + tid * 4) = o;
    return;
  }
  if (bid < 2057) {
    int r = (bid - 2048) * 256 + tid;
    if (r > N_NODES) return;
    int lo = 0, hi = NEDGE;
    while (lo < hi) { int mid = (lo + hi) >> 1; if (adj_rows[mid] < r) lo = mid + 1; else hi = mid; }
    row_ptr[r] = lo;
    return;
  }
  int tb = bid - 2057;
  const float* W; u16* Wt; int K, N;
  if (tb < 2048)      { W = W1; Wt = Wt1; K = DIM;     N = N_NODES; }
  else if (tb < 6144) { W = W2; Wt = Wt2; K = N_NODES; N = N_NODES; tb -= 2048; }
  else                { W = W3; Wt = Wt3; K = N_NODES; N = DIM;     tb -= 6144; }
  int ntx = N >> 5;
  int bx = tb % ntx;
  int by = tb / ntx;
  int tx = tid & 31, ty = tid >> 5;
  #pragma unroll
  for (int r = 0; r < 32; r += 8)
    t[r + ty][tx] = f2bf(W[(size_t)(by * 32 + r + ty) * N + bx * 32 + tx]);
  __syncthreads();
  #pragma unroll
  for (int r = 0; r < 32; r += 8)
    Wt[(size_t)(bx * 32 + r + ty) * K + by * 32 + tx] = t[tx][r + ty];
}

// ---------- SpMM task: one (row, 1024-col chunk) ----------
template <bool F32OUT>
__device__ __forceinline__ void spmm_task(const u16* __restrict__ X16,
                                          const int* __restrict__ row_ptr,
                                          const int* __restrict__ adj_cols,
                                          const float* __restrict__ adj_vals,
                                          const float* __restrict__ bias,
                                          u16* __restrict__ Y16,
                                          float* __restrict__ Y32,
                                          int width, int task) {
  int chunks = width >> 10;
  int ch = task % chunks;
  int r = task / chunks;
  int col = ch * 1024 + threadIdx.x * 4;
  int e0 = row_ptr[r], e1 = row_ptr[r + 1];
  float a0 = 0.f, a1 = 0.f, a2 = 0.f, a3 = 0.f;
  int e = e0;
  for (; e + 2 <= e1; e += 2) {
    int c0 = adj_cols[e] & (N_NODES - 1);
    int c1 = adj_cols[e + 1] & (N_NODES - 1);
    float v0 = adj_vals[e], v1 = adj_vals[e + 1];
    ushort4 x0 = *(const ushort4*)(X16 + (size_t)c0 * width + col);
    ushort4 x1 = *(const ushort4*)(X16 + (size_t)c1 * width + col);
    a0 += v0 * bf2f(x0.x) + v1 * bf2f(x1.x);
    a1 += v0 * bf2f(x0.y) + v1 * bf2f(x1.y);
    a2 += v0 * bf2f(x0.z) + v1 * bf2f(x1.z);
    a3 += v0 * bf2f(x0.w) + v1 * bf2f(x1.w);
  }
  if (e < e1) {
    int c = adj_cols[e] & (N_NODES - 1);
    float v = adj_vals[e];
    ushort4 x = *(const ushort4*)(X16 + (size_t)c * width + col);
    a0 += v * bf2f(x.x); a1 += v * bf2f(x.y);
    a2 += v * bf2f(x.z); a3 += v * bf2f(x.w);
  }
  if (F32OUT) {
    f32x4 bb = *(const f32x4*)(bias + col);
    f32x4 o; o[0] = a0 + bb[0]; o[1] = a1 + bb[1]; o[2] = a2 + bb[2]; o[3] = a3 + bb[3];
    *(f32x4*)(Y32 + (size_t)r * width + col) = o;
  } else {
    ushort4 o; o.x = f2bf(a0); o.y = f2bf(a1); o.z = f2bf(a2); o.w = f2bf(a3);
    *(ushort4*)(Y16 + (size_t)r * width + col) = o;
  }
}

// ---------- GEMM tile: 128x128, 256 thr (4 waves 2x2), BK=64, swizzled ----------
// LDS passed from kernel: As0/Bs0 each 2 bufs x 8192 u16.
template <bool BIAS, bool RELU>
__device__ __forceinline__ void gemm_tile(const u16* __restrict__ A,
                                          const u16* __restrict__ Bt,
                                          const float* __restrict__ bias,
                                          u16* __restrict__ C16,
                                          int N, int K, int tile,
                                          u16* As0, u16* Bs0) {
  const int ntx = N >> 7;
  const int bx = tile % ntx;
  const int by = tile / ntx;
  const int tid = threadIdx.x;
  const int wid = tid >> 6;
  const int lane = tid & 63;
  const int wr = wid >> 1, wc = wid & 1;
  const int rowbase = by * 128, colbase = bx * 128;

  f32x4 acc[4][4];
  #pragma unroll
  for (int i = 0; i < 4; ++i)
    #pragma unroll
    for (int j = 0; j < 4; ++j) acc[i][j] = (f32x4){0.f, 0.f, 0.f, 0.f};

  const int srow = tid >> 3;                       // 32 rows per issue
  const int skk = (((tid & 7) ^ (srow & 7)) << 3); // pre-swizzled source k

  #define MSTAGE(buf, kt)                                                       \
    do {                                                                        \
      _Pragma("unroll")                                                         \
      for (int i = 0; i < 4; ++i) {                                             \
        const u16* g = A + (size_t)(rowbase + i * 32 + srow) * K + (kt) + skk;  \
        __builtin_amdgcn_global_load_lds(                                       \
            (const __attribute__((address_space(1))) u32*)g,                    \
            (__attribute__((address_space(3))) u32*)(As0 + (buf) * 8192 + i * 2048 + tid * 8), \
            16, 0, 0);                                                          \
      }                                                                         \
      _Pragma("unroll")                                                         \
      for (int i = 0; i < 4; ++i) {                                             \
        const u16* g = Bt + (size_t)(colbase + i * 32 + srow) * K + (kt) + skk; \
        __builtin_amdgcn_global_load_lds(                                       \
            (const __attribute__((address_space(1))) u32*)g,                    \
            (__attribute__((address_space(3))) u32*)(Bs0 + (buf) * 8192 + i * 2048 + tid * 8), \
            16, 0, 0);                                                          \
      }                                                                         \
    } while (0)

  const int rrow = lane & 15;
  const int kq = (lane >> 4) * 8;
  const int rswz = (lane & 7) << 3;

  const int nk = K >> 6;
  MSTAGE(0, 0);
  __syncthreads();

  for (int t = 0; t < nk; ++t) {
    const u16* as = As0 + (t & 1) * 8192;
    const u16* bs = Bs0 + (t & 1) * 8192;
    if (t + 1 < nk) MSTAGE((t + 1) & 1, (t + 1) << 6);
    bf16x8 af[4][2], bfr[4][2];
    #pragma unroll
    for (int mi = 0; mi < 4; ++mi) {
      int r = wr * 64 + mi * 16 + rrow;
      #pragma unroll
      for (int h = 0; h < 2; ++h)
        af[mi][h] = *(const bf16x8*)(as + r * 64 + ((h * 32 + kq) ^ rswz));
    }
    #pragma unroll
    for (int ni = 0; ni < 4; ++ni) {
      int c = wc * 64 + ni * 16 + rrow;
      #pragma unroll
      for (int h = 0; h < 2; ++h)
        bfr[ni][h] = *(const bf16x8*)(bs + c * 64 + ((h * 32 + kq) ^ rswz));
    }
    #pragma unroll
    for (int h = 0; h < 2; ++h)
      #pragma unroll
      for (int mi = 0; mi < 4; ++mi)
        #pragma unroll
        for (int ni = 0; ni < 4; ++ni)
          acc[mi][ni] = __builtin_amdgcn_mfma_f32_16x16x32_bf16(af[mi][h], bfr[ni][h], acc[mi][ni], 0, 0, 0);
    __syncthreads();
  }
  #undef MSTAGE

  #pragma unroll
  for (int mi = 0; mi < 4; ++mi) {
    #pragma unroll
    for (int ni = 0; ni < 4; ++ni) {
      int col = colbase + wc * 64 + ni * 16 + rrow;
      float bv = BIAS ? bias[col] : 0.f;
      #pragma unroll
      for (int j = 0; j < 4; ++j) {
        int row = rowbase + wr * 64 + mi * 16 + (lane >> 4) * 4 + j;
        float v = acc[mi][ni][j] + bv;
        if (RELU) v = fmaxf(v, 0.f);
        C16[(size_t)row * N + col] = f2bf(v);
      }
    }
  }
}

// ---------- inter-block barrier for compute crew (all co-resident) ----------
__device__ __forceinline__ void xbar(int* sync, int p) {
  __syncthreads();
  if (threadIdx.x == 0) {
    __builtin_amdgcn_fence(__ATOMIC_RELEASE, "agent");
    __hip_atomic_fetch_add(&sync[p], 1, __ATOMIC_RELAXED, __HIP_MEMORY_SCOPE_AGENT);
    while (__hip_atomic_load(&sync[p], __ATOMIC_RELAXED, __HIP_MEMORY_SCOPE_AGENT) < NC)
      __builtin_amdgcn_s_sleep(8);
    __builtin_amdgcn_fence(__ATOMIC_ACQUIRE, "agent");
  }
  __syncthreads();
}

// ---------- mega: compute crew (chain, phase-barriered) || copy crew ----------
__global__ __launch_bounds__(256, 2) void k_mega(
    const u16* __restrict__ A1, u16* __restrict__ S, u16* __restrict__ H,
    u16* __restrict__ X3, float* __restrict__ logits,
    const u16* __restrict__ Wt1, const u16* __restrict__ Wt2, const u16* __restrict__ Wt3,
    const float* __restrict__ b1, const float* __restrict__ b2, const float* __restrict__ b3,
    const int* __restrict__ row_ptr, const int* __restrict__ adj_cols,
    const float* __restrict__ adj_vals,
    const float* __restrict__ feat, float* __restrict__ out,
    int* __restrict__ sync) {
  __shared__ __align__(16) u16 AsB[2 * 8192];
  __shared__ __align__(16) u16 BsB[2 * 8192];
  const int bid = blockIdx.x;
  if (bid >= NC) {
    // copy crew: slots 2..6, 2560 tasks x 32 rows
    for (int t = bid - NC; t < 2560; t += NCOPY)
      copy_feat_rows(feat, out, t * 32, threadIdx.x);
    return;
  }
  // compute crew
  for (int t = bid; t < 2048; t += NC)
    spmm_task<false>(A1, row_ptr, adj_cols, adj_vals, nullptr, S, nullptr, DIM, t);
  xbar(sync, 0);
  for (int t = bid; t < 256; t += NC)
    gemm_tile<true, true>(S, Wt1, b1, H, N_NODES, DIM, t, AsB, BsB);
  xbar(sync, 1);
  for (int t = bid; t < 4096; t += NC)
    spmm_task<false>(H, row_ptr, adj_cols, adj_vals, nullptr, S, nullptr, N_NODES, t);
  xbar(sync, 2);
  for (int t = bid; t < 256; t += NC)
    gemm_tile<true, false>(S, Wt2, b2, H, N_NODES, N_NODES, t, AsB, BsB);
  xbar(sync, 3);
  for (int t = bid; t < 128; t += NC)
    gemm_tile<false, false>(H, Wt3, nullptr, X3, DIM, N_NODES, t, AsB, BsB);
  xbar(sync, 4);
  for (int t = bid; t < 2048; t += NC)
    spmm_task<true>(X3, row_ptr, adj_cols, adj_vals, b3, nullptr, logits, DIM, t);
}

// ---------- tail: slots 0/1 gather from logits ----------
__global__ __launch_bounds__(256) void k_assemble2(const float* __restrict__ logits,
                                                   const int* __restrict__ dx,
                                                   const int* __restrict__ flag,
                                                   float* __restrict__ out) {
  int i = blockIdx.x;  // 0 .. 2B-1
  int b = i >> 1, slot = i & 1;
  int f = *flag;
  long p = 7L * b + (slot == 0 ? 1 : 0);  // slot0 -> e2, slot1 -> e1
  int node = dx[f ? 2 * p : p] & (N_NODES - 1);
  f32x4 v = *(const f32x4*)(logits + (size_t)node * DIM + threadIdx.x * 4);
  __builtin_nontemporal_store(v, (f32x4*)(out + ((size_t)b * 7 + slot) * DIM + threadIdx.x * 4));
}

extern "C" void kernel_launch(void* const* d_in, const int* in_sizes, int n_in,
                              void* d_out, int out_size, void* d_ws, size_t ws_size,
                              hipStream_t stream) {
  const float* feat   = (const float*)d_in[0];
  const int* data_x   = (const int*)d_in[1];
  const int* adj_rows = (const int*)d_in[2];
  const int* adj_cols = (const int*)d_in[3];
  const float* adj_vals = (const float*)d_in[4];
  const float* W1 = (const float*)d_in[5];
  const float* b1 = (const float*)d_in[6];
  const float* W2 = (const float*)d_in[7];
  const float* b2 = (const float*)d_in[8];
  const float* W3 = (const float*)d_in[9];
  const float* b3 = (const float*)d_in[10];
  float* out = (float*)d_out;

  char* ws = (char*)d_ws;
  size_t off = 0;
  auto alloc = [&](size_t bytes) {
    char* p = ws + off; off += (bytes + 511) & ~(size_t)511; return p;
  };
  int*  flag    = (int*)alloc(4);
  int*  sync    = (int*)alloc(32);
  int*  counts  = (int*)alloc(N_NODES * 4);
  int*  bucket  = (int*)alloc((size_t)N_NODES * CAP * 4);
  int*  row_ptr = (int*)alloc((N_NODES + 1) * 4);
  u16*  A1      = (u16*)alloc((size_t)N_NODES * DIM * 2);        // 4 MB
  u16*  S       = (u16*)alloc((size_t)N_NODES * N_NODES * 2);    // 8 MB
  u16*  H       = (u16*)alloc((size_t)N_NODES * N_NODES * 2);    // 8 MB
  u16*  X3      = (u16*)alloc((size_t)N_NODES * DIM * 2);        // 4 MB
  u16*  Wt1     = (u16*)alloc((size_t)DIM * N_NODES * 2);        // 4 MB
  u16*  Wt2     = (u16*)alloc((size_t)N_NODES * N_NODES * 2);    // 8 MB
  u16*  Wt3     = (u16*)alloc((size_t)N_NODES * DIM * 2);        // 4 MB
  float* logits = (float*)alloc((size_t)N_NODES * DIM * 4);      // 8 MB

  hipMemsetAsync(counts, 0, N_NODES * 4, stream);
  hipMemsetAsync(sync, 0, 32, stream);
  k_bucket<<<(2 * BATCH + 255) / 256, 256, 0, stream>>>(data_x, flag, counts, bucket);
  k_prep2<<<2057 + 8192, 256, 0, stream>>>(feat, counts, bucket, A1, adj_rows, row_ptr,
                                           W1, W2, W3, Wt1, Wt2, Wt3);
  k_mega<<<NC + NCOPY, 256, 0, stream>>>(A1, S, H, X3, logits, Wt1, Wt2, Wt3,
                                         b1, b2, b3, row_ptr, adj_cols, adj_vals,
                                         feat, out, sync);
  k_assemble2<<<2 * BATCH, 256, 0, stream>>>(logits, data_x, flag, out);
}

// Round 12
// 337.748 us; speedup vs baseline: 1.5398x; 1.5398x over previous
//
#include <hip/hip_runtime.h>
#include <stdint.h>

#define N_NODES 2048
#define DIM 1024
#define BATCH 16384
#define NEDGE 65536
#define CAP 96

typedef __bf16 bf16x8 __attribute__((ext_vector_type(8)));
typedef float f32x4 __attribute__((ext_vector_type(4)));
typedef unsigned short u16;
typedef unsigned int u32;

__device__ __forceinline__ float bf2f(u16 u) {
  union { u32 i; float f; } v; v.i = ((u32)u) << 16; return v.f;
}
__device__ __forceinline__ u16 f2bf(float f) {
  union { float f; u32 i; } v; v.f = f;
  u32 r = v.i + 0x7fffu + ((v.i >> 16) & 1u);
  return (u16)(r >> 16);
}

// ---------- bucket fill; detects int64-vs-int32 inline ----------
__global__ __launch_bounds__(256) void k_bucket(const int* __restrict__ dx,
                                                int* __restrict__ flag,
                                                int* __restrict__ counts,
                                                int* __restrict__ bucket) {
  int is64 = 1;
  for (int j = 0; j < 32; ++j)
    if (dx[2 * j + 1] != 0) { is64 = 0; break; }
  if (blockIdx.x == 0 && threadIdx.x == 0) *flag = is64;
  int i = blockIdx.x * 256 + threadIdx.x;
  if (i >= 2 * BATCH) return;
  long p = (i < BATCH) ? 7L * i : 7L * (i - BATCH) + 1;
  int n = dx[is64 ? 2 * p : p] & (N_NODES - 1);
  int slot = atomicAdd(&counts[n], 1);
  if (slot < CAP) bucket[n * CAP + slot] = i;
}

// ---------- merged: nodesum (2048) | rowptr (9) | transpose3 (8192) ----------
__global__ __launch_bounds__(256) void k_prep2(const float* __restrict__ feat,
                                               const int* __restrict__ counts,
                                               const int* __restrict__ bucket,
                                               u16* __restrict__ A1,
                                               const int* __restrict__ adj_rows,
                                               int* __restrict__ row_ptr,
                                               const float* __restrict__ W1,
                                               const float* __restrict__ W2,
                                               const float* __restrict__ W3,
                                               u16* __restrict__ Wt1,
                                               u16* __restrict__ Wt2,
                                               u16* __restrict__ Wt3) {
  __shared__ __align__(16) u16 t[32][33];
  int bid = blockIdx.x;
  int tid = threadIdx.x;
  if (bid < 2048) {
    int n = bid;
    int cnt = counts[n]; if (cnt > CAP) cnt = CAP;
    float a0 = 0.f, a1 = 0.f, a2 = 0.f, a3 = 0.f;
    for (int j = 0; j < cnt; ++j) {
      int i = bucket[n * CAP + j];
      size_t rowoff = (i < BATCH) ? ((size_t)i * 7) * DIM
                                  : ((size_t)(i - BATCH) * 7 + 1) * DIM;
      f32x4 v = *(const f32x4*)(feat + rowoff + tid * 4);
      a0 += v[0]; a1 += v[1]; a2 += v[2]; a3 += v[3];
    }
    ushort4 o; o.x = f2bf(a0); o.y = f2bf(a1); o.z = f2bf(a2); o.w = f2bf(a3);
    *(ushort4*)(A1 + (size_t)n * DIM + tid * 4) = o;
    return;
  }
  if (bid < 2057) {
    int r = (bid - 2048) * 256 + tid;
    if (r > N_NODES) return;
    int lo = 0, hi = NEDGE;
    while (lo < hi) { int mid = (lo + hi) >> 1; if (adj_rows[mid] < r) lo = mid + 1; else hi = mid; }
    row_ptr[r] = lo;
    return;
  }
  int tb = bid - 2057;
  const float* W; u16* Wt; int K, N;
  if (tb < 2048)      { W = W1; Wt = Wt1; K = DIM;     N = N_NODES; }
  else if (tb < 6144) { W = W2; Wt = Wt2; K = N_NODES; N = N_NODES; tb -= 2048; }
  else                { W = W3; Wt = Wt3; K = N_NODES; N = DIM;     tb -= 6144; }
  int ntx = N >> 5;
  int bx = tb % ntx;
  int by = tb / ntx;
  int tx = tid & 31, ty = tid >> 5;
  #pragma unroll
  for (int r = 0; r < 32; r += 8)
    t[r + ty][tx] = f2bf(W[(size_t)(by * 32 + r + ty) * N + bx * 32 + tx]);
  __syncthreads();
  #pragma unroll
  for (int r = 0; r < 32; r += 8)
    Wt[(size_t)(bx * 32 + r + ty) * K + by * 32 + tx] = t[tx][r + ty];
}

// ---------- SpMM (CSR), bf16 X -> bf16 Y16, or f32(+bias) Y32 ----------
template <bool F32OUT>
__global__ __launch_bounds__(256) void k_spmm(const u16* __restrict__ X16,
                                              const int* __restrict__ row_ptr,
                                              const int* __restrict__ adj_cols,
                                              const float* __restrict__ adj_vals,
                                              const float* __restrict__ bias,
                                              u16* __restrict__ Y16,
                                              float* __restrict__ Y32,
                                              int width) {
  int chunks = width >> 10;  // 1024 cols per block (4 per thread)
  int ch = blockIdx.x % chunks;
  int r = blockIdx.x / chunks;
  int col = ch * 1024 + threadIdx.x * 4;
  int e0 = row_ptr[r], e1 = row_ptr[r + 1];
  float a0 = 0.f, a1 = 0.f, a2 = 0.f, a3 = 0.f;
  int e = e0;
  for (; e + 4 <= e1; e += 4) {
    int c0 = adj_cols[e] & (N_NODES - 1);
    int c1 = adj_cols[e + 1] & (N_NODES - 1);
    int c2 = adj_cols[e + 2] & (N_NODES - 1);
    int c3 = adj_cols[e + 3] & (N_NODES - 1);
    float v0 = adj_vals[e], v1 = adj_vals[e + 1];
    float v2 = adj_vals[e + 2], v3 = adj_vals[e + 3];
    ushort4 x0 = *(const ushort4*)(X16 + (size_t)c0 * width + col);
    ushort4 x1 = *(const ushort4*)(X16 + (size_t)c1 * width + col);
    ushort4 x2 = *(const ushort4*)(X16 + (size_t)c2 * width + col);
    ushort4 x3 = *(const ushort4*)(X16 + (size_t)c3 * width + col);
    a0 += v0 * bf2f(x0.x) + v1 * bf2f(x1.x) + v2 * bf2f(x2.x) + v3 * bf2f(x3.x);
    a1 += v0 * bf2f(x0.y) + v1 * bf2f(x1.y) + v2 * bf2f(x2.y) + v3 * bf2f(x3.y);
    a2 += v0 * bf2f(x0.z) + v1 * bf2f(x1.z) + v2 * bf2f(x2.z) + v3 * bf2f(x3.z);
    a3 += v0 * bf2f(x0.w) + v1 * bf2f(x1.w) + v2 * bf2f(x2.w) + v3 * bf2f(x3.w);
  }
  for (; e < e1; ++e) {
    int c = adj_cols[e] & (N_NODES - 1);
    float v = adj_vals[e];
    ushort4 x = *(const ushort4*)(X16 + (size_t)c * width + col);
    a0 += v * bf2f(x.x); a1 += v * bf2f(x.y);
    a2 += v * bf2f(x.z); a3 += v * bf2f(x.w);
  }
  if (F32OUT) {
    f32x4 bb = *(const f32x4*)(bias + col);
    f32x4 o; o[0] = a0 + bb[0]; o[1] = a1 + bb[1]; o[2] = a2 + bb[2]; o[3] = a3 + bb[3];
    *(f32x4*)(Y32 + (size_t)r * width + col) = o;
  } else {
    ushort4 o; o.x = f2bf(a0); o.y = f2bf(a1); o.z = f2bf(a2); o.w = f2bf(a3);
    *(ushort4*)(Y16 + (size_t)r * width + col) = o;
  }
}

// ---------- MFMA GEMM, 2-phase double-buffered, BK=64, swizzled LDS ----------
template <int BM, int BN, int THREADS, bool BIAS, bool RELU>
__global__ __launch_bounds__(THREADS) void k_gemm(const u16* __restrict__ A,
                                                  const u16* __restrict__ Bt,
                                                  const float* __restrict__ bias,
                                                  u16* __restrict__ C16,
                                                  int M, int N, int K) {
  constexpr int BK = 64;
  constexpr int WAVES_N = THREADS / 128;
  constexpr int WM = BM / 2, WN = BN / WAVES_N;
  constexpr int MI = WM / 16, NI = WN / 16;
  constexpr int RPI = THREADS / 8;
  constexpr int IA = BM / RPI, IB = BN / RPI;
  __shared__ __align__(16) u16 As[2][BM * BK];
  __shared__ __align__(16) u16 Bs[2][BN * BK];
  const int ntx = N / BN;
  const int bx = blockIdx.x % ntx;
  const int by = blockIdx.x / ntx;
  const int tid = threadIdx.x;
  const int wid = tid >> 6;
  const int lane = tid & 63;
  const int wr = wid / WAVES_N, wc = wid % WAVES_N;
  const int rowbase = by * BM, colbase = bx * BN;

  f32x4 acc[MI][NI];
  #pragma unroll
  for (int i = 0; i < MI; ++i)
    #pragma unroll
    for (int j = 0; j < NI; ++j) acc[i][j] = (f32x4){0.f, 0.f, 0.f, 0.f};

  const int srow = tid >> 3;
  const int skk = (((tid & 7) ^ (srow & 7)) << 3);

  #define STAGE(buf, kt)                                                        \
    do {                                                                        \
      _Pragma("unroll")                                                         \
      for (int i = 0; i < IA; ++i) {                                            \
        const u16* g = A + (size_t)(rowbase + i * RPI + srow) * K + (kt) + skk; \
        __builtin_amdgcn_global_load_lds(                                       \
            (const __attribute__((address_space(1))) u32*)g,                    \
            (__attribute__((address_space(3))) u32*)(&As[buf][i * (RPI * 64) + tid * 8]), \
            16, 0, 0);                                                          \
      }                                                                         \
      _Pragma("unroll")                                                         \
      for (int i = 0; i < IB; ++i) {                                            \
        const u16* g = Bt + (size_t)(colbase + i * RPI + srow) * K + (kt) + skk;\
        __builtin_amdgcn_global_load_lds(                                       \
            (const __attribute__((address_space(1))) u32*)g,                    \
            (__attribute__((address_space(3))) u32*)(&Bs[buf][i * (RPI * 64) + tid * 8]), \
            16, 0, 0);                                                          \
      }                                                                         \
    } while (0)

  const int rrow = lane & 15;
  const int kq = (lane >> 4) * 8;
  const int rswz = (lane & 7) << 3;

  const int nk = K >> 6;
  STAGE(0, 0);
  __syncthreads();

  for (int t = 0; t < nk; ++t) {
    const u16* as = As[t & 1];
    const u16* bs = Bs[t & 1];
    if (t + 1 < nk) STAGE((t + 1) & 1, (t + 1) << 6);
    bf16x8 af[MI][2], bfr[NI][2];
    #pragma unroll
    for (int mi = 0; mi < MI; ++mi) {
      int r = wr * WM + mi * 16 + rrow;
      #pragma unroll
      for (int h = 0; h < 2; ++h)
        af[mi][h] = *(const bf16x8*)(as + r * 64 + ((h * 32 + kq) ^ rswz));
    }
    #pragma unroll
    for (int ni = 0; ni < NI; ++ni) {
      int c = wc * WN + ni * 16 + rrow;
      #pragma unroll
      for (int h = 0; h < 2; ++h)
        bfr[ni][h] = *(const bf16x8*)(bs + c * 64 + ((h * 32 + kq) ^ rswz));
    }
    #pragma unroll
    for (int h = 0; h < 2; ++h)
      #pragma unroll
      for (int mi = 0; mi < MI; ++mi)
        #pragma unroll
        for (int ni = 0; ni < NI; ++ni)
          acc[mi][ni] = __builtin_amdgcn_mfma_f32_16x16x32_bf16(af[mi][h], bfr[ni][h], acc[mi][ni], 0, 0, 0);
    __syncthreads();
  }
  #undef STAGE

  #pragma unroll
  for (int mi = 0; mi < MI; ++mi) {
    #pragma unroll
    for (int ni = 0; ni < NI; ++ni) {
      int col = colbase + wc * WN + ni * 16 + rrow;
      float bv = BIAS ? bias[col] : 0.f;
      #pragma unroll
      for (int j = 0; j < 4; ++j) {
        int row = rowbase + wr * WM + mi * 16 + (lane >> 4) * 4 + j;
        float v = acc[mi][ni][j] + bv;
        if (RELU) v = fmaxf(v, 0.f);
        C16[(size_t)row * N + col] = f2bf(v);
      }
    }
  }
}

// ---------- output assembly: 8 rows per block ----------
// row = b*7+slot; feat[b,slot,:] == feat + row*DIM (same layout as out).
__global__ __launch_bounds__(256) void k_assemble(const float* __restrict__ feat,
                                                  const float* __restrict__ logits,
                                                  const int* __restrict__ dx,
                                                  const int* __restrict__ flag,
                                                  float* __restrict__ out) {
  int row = blockIdx.x * 8 + (threadIdx.x >> 5);  // 0 .. B*7-1
  int tc = threadIdx.x & 31;
  int b = row / 7, slot = row - b * 7;
  float* dst = out + (size_t)row * DIM;
  if (slot <= 1) {
    int f = *flag;
    long p = 7L * b + (slot == 0 ? 1 : 0);  // slot0 -> e2, slot1 -> e1
    int node = dx[f ? 2 * p : p] & (N_NODES - 1);
    const float* src = logits + (size_t)node * DIM;  // L3-resident, reuse ~16x: cached loads
    #pragma unroll
    for (int j = 0; j < 8; ++j) {
      f32x4 v = *(const f32x4*)(src + (tc + j * 32) * 4);
      __builtin_nontemporal_store(v, (f32x4*)(dst + (tc + j * 32) * 4));
    }
  } else {
    const float* src = feat + (size_t)row * DIM;  // single-use: NT both sides
    #pragma unroll
    for (int j = 0; j < 8; ++j) {
      f32x4 v = __builtin_nontemporal_load((const f32x4*)(src + (tc + j * 32) * 4));
      __builtin_nontemporal_store(v, (f32x4*)(dst + (tc + j * 32) * 4));
    }
  }
}

extern "C" void kernel_launch(void* const* d_in, const int* in_sizes, int n_in,
                              void* d_out, int out_size, void* d_ws, size_t ws_size,
                              hipStream_t stream) {
  const float* feat   = (const float*)d_in[0];
  const int* data_x   = (const int*)d_in[1];
  const int* adj_rows = (const int*)d_in[2];
  const int* adj_cols = (const int*)d_in[3];
  const float* adj_vals = (const float*)d_in[4];
  const float* W1 = (const float*)d_in[5];
  const float* b1 = (const float*)d_in[6];
  const float* W2 = (const float*)d_in[7];
  const float* b2 = (const float*)d_in[8];
  const float* W3 = (const float*)d_in[9];
  const float* b3 = (const float*)d_in[10];
  float* out = (float*)d_out;

  char* ws = (char*)d_ws;
  size_t off = 0;
  auto alloc = [&](size_t bytes) {
    char* p = ws + off; off += (bytes + 511) & ~(size_t)511; return p;
  };
  int*  flag    = (int*)alloc(4);
  int*  counts  = (int*)alloc(N_NODES * 4);
  int*  bucket  = (int*)alloc((size_t)N_NODES * CAP * 4);
  int*  row_ptr = (int*)alloc((N_NODES + 1) * 4);
  u16*  A1      = (u16*)alloc((size_t)N_NODES * DIM * 2);
  u16*  S       = (u16*)alloc((size_t)N_NODES * N_NODES * 2);
  u16*  H       = (u16*)alloc((size_t)N_NODES * N_NODES * 2);
  u16*  X3      = (u16*)alloc((size_t)N_NODES * DIM * 2);
  u16*  Wt1     = (u16*)alloc((size_t)DIM * N_NODES * 2);
  u16*  Wt2     = (u16*)alloc((size_t)N_NODES * N_NODES * 2);
  u16*  Wt3     = (u16*)alloc((size_t)N_NODES * DIM * 2);
  float* logits = (float*)alloc((size_t)N_NODES * DIM * 4);

  hipMemsetAsync(counts, 0, N_NODES * 4, stream);
  k_bucket<<<(2 * BATCH + 255) / 256, 256, 0, stream>>>(data_x, flag, counts, bucket);
  k_prep2<<<2057 + 8192, 256, 0, stream>>>(feat, counts, bucket, A1, adj_rows, row_ptr,
                                           W1, W2, W3, Wt1, Wt2, Wt3);

  // layer 1: S1 = spmm(A1) [w=1024]; H1 = relu(S1 @ W1 + b1)
  k_spmm<false><<<2048, 256, 0, stream>>>(A1, row_ptr, adj_cols, adj_vals, nullptr, S,
                                          nullptr, DIM);
  k_gemm<128, 128, 512, true, true><<<256, 512, 0, stream>>>(S, Wt1, b1, H, N_NODES, N_NODES, DIM);
  // layer 2: S2 = spmm(H1) [w=2048]; H2 = S2 @ W2 + b2
  k_spmm<false><<<4096, 256, 0, stream>>>(H, row_ptr, adj_cols, adj_vals, nullptr, S,
                                          nullptr, N_NODES);
  k_gemm<128, 128, 512, true, false><<<256, 512, 0, stream>>>(S, Wt2, b2, H, N_NODES, N_NODES, N_NODES);
  // layer 3: X3 = H2 @ W3 ; logits = spmm(X3) + b3 [f32]
  k_gemm<128, 64, 256, false, false><<<256, 256, 0, stream>>>(H, Wt3, nullptr, X3, N_NODES, DIM, N_NODES);
  k_spmm<true><<<2048, 256, 0, stream>>>(X3, row_ptr, adj_cols, adj_vals, b3, nullptr,
                                         logits, DIM);

  // assemble all 7 slots, 8 rows per block
  k_assemble<<<BATCH * 7 / 8, 256, 0, stream>>>(feat, logits, data_x, flag, out);
}

// Round 13
// 316.902 us; speedup vs baseline: 1.6411x; 1.0658x over previous
//
#include <hip/hip_runtime.h>
#include <stdint.h>

#define N_NODES 2048
#define DIM 1024
#define BATCH 16384
#define NEDGE 65536
#define CAP 96

typedef __bf16 bf16x8 __attribute__((ext_vector_type(8)));
typedef float f32x4 __attribute__((ext_vector_type(4)));
typedef unsigned short u16;
typedef unsigned int u32;

__device__ __forceinline__ float bf2f(u16 u) {
  union { u32 i; float f; } v; v.i = ((u32)u) << 16; return v.f;
}
__device__ __forceinline__ u16 f2bf(float f) {
  union { float f; u32 i; } v; v.f = f;
  u32 r = v.i + 0x7fffu + ((v.i >> 16) & 1u);
  return (u16)(r >> 16);
}

// ---------- bucket fill; detects int64-vs-int32 inline ----------
__global__ __launch_bounds__(256) void k_bucket(const int* __restrict__ dx,
                                                int* __restrict__ flag,
                                                int* __restrict__ counts,
                                                int* __restrict__ bucket) {
  int is64 = 1;
  for (int j = 0; j < 32; ++j)
    if (dx[2 * j + 1] != 0) { is64 = 0; break; }
  if (blockIdx.x == 0 && threadIdx.x == 0) *flag = is64;  // for k_assemble
  int i = blockIdx.x * 256 + threadIdx.x;
  if (i >= 2 * BATCH) return;
  long p = (i < BATCH) ? 7L * i : 7L * (i - BATCH) + 1;
  int n = dx[is64 ? 2 * p : p] & (N_NODES - 1);
  int slot = atomicAdd(&counts[n], 1);
  if (slot < CAP) bucket[n * CAP + slot] = i;
}

// ---------- merged: nodesum (2048) | rowptr (9) | transpose3 (8192) ----------
__global__ __launch_bounds__(256) void k_prep2(const float* __restrict__ feat,
                                               const int* __restrict__ counts,
                                               const int* __restrict__ bucket,
                                               u16* __restrict__ A1,
                                               const int* __restrict__ adj_rows,
                                               int* __restrict__ row_ptr,
                                               const float* __restrict__ W1,
                                               const float* __restrict__ W2,
                                               const float* __restrict__ W3,
                                               u16* __restrict__ Wt1,
                                               u16* __restrict__ Wt2,
                                               u16* __restrict__ Wt3) {
  __shared__ __align__(16) u16 t[32][33];
  int bid = blockIdx.x;
  int tid = threadIdx.x;
  if (bid < 2048) {
    // -------- nodesum: per-node segment sum (f32 in) -> A1 (bf16) --------
    int n = bid;
    int cnt = counts[n]; if (cnt > CAP) cnt = CAP;
    float a0 = 0.f, a1 = 0.f, a2 = 0.f, a3 = 0.f;
    for (int j = 0; j < cnt; ++j) {
      int i = bucket[n * CAP + j];
      size_t rowoff = (i < BATCH) ? ((size_t)i * 7) * DIM
                                  : ((size_t)(i - BATCH) * 7 + 1) * DIM;
      f32x4 v = *(const f32x4*)(feat + rowoff + tid * 4);
      a0 += v[0]; a1 += v[1]; a2 += v[2]; a3 += v[3];
    }
    ushort4 o; o.x = f2bf(a0); o.y = f2bf(a1); o.z = f2bf(a2); o.w = f2bf(a3);
    *(ushort4*)(A1 + (size_t)n * DIM + tid * 4) = o;
    return;
  }
  if (bid < 2057) {
    // -------- CSR row_ptr via binary search over sorted adj_rows --------
    int r = (bid - 2048) * 256 + tid;
    if (r > N_NODES) return;
    int lo = 0, hi = NEDGE;
    while (lo < hi) { int mid = (lo + hi) >> 1; if (adj_rows[mid] < r) lo = mid + 1; else hi = mid; }
    row_ptr[r] = lo;
    return;
  }
  // -------- weight transpose (K x N, f32) -> (N x K, bf16) --------
  int tb = bid - 2057;
  const float* W; u16* Wt; int K, N;
  if (tb < 2048)      { W = W1; Wt = Wt1; K = DIM;     N = N_NODES; }
  else if (tb < 6144) { W = W2; Wt = Wt2; K = N_NODES; N = N_NODES; tb -= 2048; }
  else                { W = W3; Wt = Wt3; K = N_NODES; N = DIM;     tb -= 6144; }
  int ntx = N >> 5;
  int bx = tb % ntx;
  int by = tb / ntx;
  int tx = tid & 31, ty = tid >> 5;  // 32 x 8
  #pragma unroll
  for (int r = 0; r < 32; r += 8)
    t[r + ty][tx] = f2bf(W[(size_t)(by * 32 + r + ty) * N + bx * 32 + tx]);
  __syncthreads();
  #pragma unroll
  for (int r = 0; r < 32; r += 8)
    Wt[(size_t)(bx * 32 + r + ty) * K + by * 32 + tx] = t[tx][r + ty];
}

// ---------- SpMM (CSR), bf16 X -> bf16 Y16, or f32(+bias) Y32 ----------
template <bool F32OUT>
__global__ __launch_bounds__(256) void k_spmm(const u16* __restrict__ X16,
                                              const int* __restrict__ row_ptr,
                                              const int* __restrict__ adj_cols,
                                              const float* __restrict__ adj_vals,
                                              const float* __restrict__ bias,
                                              u16* __restrict__ Y16,
                                              float* __restrict__ Y32,
                                              int width) {
  int chunks = width >> 10;  // 1024 cols per block (4 per thread)
  int ch = blockIdx.x % chunks;
  int r = blockIdx.x / chunks;
  int col = ch * 1024 + threadIdx.x * 4;
  int e0 = row_ptr[r], e1 = row_ptr[r + 1];
  float a0 = 0.f, a1 = 0.f, a2 = 0.f, a3 = 0.f;
  int e = e0;
  for (; e + 2 <= e1; e += 2) {
    int c0 = adj_cols[e] & (N_NODES - 1);
    int c1 = adj_cols[e + 1] & (N_NODES - 1);
    float v0 = adj_vals[e], v1 = adj_vals[e + 1];
    ushort4 x0 = *(const ushort4*)(X16 + (size_t)c0 * width + col);
    ushort4 x1 = *(const ushort4*)(X16 + (size_t)c1 * width + col);
    a0 += v0 * bf2f(x0.x) + v1 * bf2f(x1.x);
    a1 += v0 * bf2f(x0.y) + v1 * bf2f(x1.y);
    a2 += v0 * bf2f(x0.z) + v1 * bf2f(x1.z);
    a3 += v0 * bf2f(x0.w) + v1 * bf2f(x1.w);
  }
  if (e < e1) {
    int c = adj_cols[e] & (N_NODES - 1);
    float v = adj_vals[e];
    ushort4 x = *(const ushort4*)(X16 + (size_t)c * width + col);
    a0 += v * bf2f(x.x); a1 += v * bf2f(x.y);
    a2 += v * bf2f(x.z); a3 += v * bf2f(x.w);
  }
  if (F32OUT) {
    f32x4 bb = *(const f32x4*)(bias + col);
    f32x4 o; o[0] = a0 + bb[0]; o[1] = a1 + bb[1]; o[2] = a2 + bb[2]; o[3] = a3 + bb[3];
    *(f32x4*)(Y32 + (size_t)r * width + col) = o;
  } else {
    ushort4 o; o.x = f2bf(a0); o.y = f2bf(a1); o.z = f2bf(a2); o.w = f2bf(a3);
    *(ushort4*)(Y16 + (size_t)r * width + col) = o;
  }
}

// ---------- MFMA GEMM, 2-phase double-buffered, BK=64, swizzled LDS ----------
// C(MxN,bf16) = A(MxK,bf16) * Bt(NxK,bf16)^T  [+bias, +relu]
// THREADS threads = THREADS/64 waves in 2 x (THREADS/128) layout.
template <int BM, int BN, int THREADS, bool BIAS, bool RELU>
__global__ __launch_bounds__(THREADS) void k_gemm(const u16* __restrict__ A,
                                                  const u16* __restrict__ Bt,
                                                  const float* __restrict__ bias,
                                                  u16* __restrict__ C16,
                                                  int M, int N, int K) {
  constexpr int BK = 64;                        // u16 elements per K-step
  constexpr int WAVES_N = THREADS / 128;        // 2 wave-rows
  constexpr int WM = BM / 2, WN = BN / WAVES_N;
  constexpr int MI = WM / 16, NI = WN / 16;
  constexpr int RPI = THREADS / 8;              // rows staged per issue
  constexpr int IA = BM / RPI, IB = BN / RPI;   // staging issues
  __shared__ __align__(16) u16 As[2][BM * BK];
  __shared__ __align__(16) u16 Bs[2][BN * BK];
  const int ntx = N / BN;
  const int bx = blockIdx.x % ntx;
  const int by = blockIdx.x / ntx;
  const int tid = threadIdx.x;
  const int wid = tid >> 6;
  const int lane = tid & 63;
  const int wr = wid / WAVES_N, wc = wid % WAVES_N;
  const int rowbase = by * BM, colbase = bx * BN;

  f32x4 acc[MI][NI];
  #pragma unroll
  for (int i = 0; i < MI; ++i)
    #pragma unroll
    for (int j = 0; j < NI; ++j) acc[i][j] = (f32x4){0.f, 0.f, 0.f, 0.f};

  // staging: thread t covers row (t>>3) of each RPI-row issue, 16B of k.
  // source k pre-swizzled so linear LDS dest + swizzled read match (rule 21).
  const int srow = tid >> 3;
  const int skk = (((tid & 7) ^ (srow & 7)) << 3);

  #define STAGE(buf, kt)                                                        \
    do {                                                                        \
      _Pragma("unroll")                                                         \
      for (int i = 0; i < IA; ++i) {                                            \
        const u16* g = A + (size_t)(rowbase + i * RPI + srow) * K + (kt) + skk; \
        __builtin_amdgcn_global_load_lds(                                       \
            (const __attribute__((address_space(1))) u32*)g,                    \
            (__attribute__((address_space(3))) u32*)(&As[buf][i * (RPI * 64) + tid * 8]), \
            16, 0, 0);                                                          \
      }                                                                         \
      _Pragma("unroll")                                                         \
      for (int i = 0; i < IB; ++i) {                                            \
        const u16* g = Bt + (size_t)(colbase + i * RPI + srow) * K + (kt) + skk;\
        __builtin_amdgcn_global_load_lds(                                       \
            (const __attribute__((address_space(1))) u32*)g,                    \
            (__attribute__((address_space(3))) u32*)(&Bs[buf][i * (RPI * 64) + tid * 8]), \
            16, 0, 0);                                                          \
      }                                                                         \
    } while (0)

  const int rrow = lane & 15;
  const int kq = (lane >> 4) * 8;       // u16 offset within 32-wide k half
  const int rswz = (lane & 7) << 3;     // read-side XOR (row&7)

  const int nk = K >> 6;
  STAGE(0, 0);
  __syncthreads();  // vmcnt(0) drain + barrier: buf0 ready

  for (int t = 0; t < nk; ++t) {
    const u16* as = As[t & 1];
    const u16* bs = Bs[t & 1];
    if (t + 1 < nk) STAGE((t + 1) & 1, (t + 1) << 6);  // overlap with compute
    bf16x8 af[MI][2], bfr[NI][2];
    #pragma unroll
    for (int mi = 0; mi < MI; ++mi) {
      int r = wr * WM + mi * 16 + rrow;
      #pragma unroll
      for (int h = 0; h < 2; ++h)
        af[mi][h] = *(const bf16x8*)(as + r * 64 + ((h * 32 + kq) ^ rswz));
    }
    #pragma unroll
    for (int ni = 0; ni < NI; ++ni) {
      int c = wc * WN + ni * 16 + rrow;
      #pragma unroll
      for (int h = 0; h < 2; ++h)
        bfr[ni][h] = *(const bf16x8*)(bs + c * 64 + ((h * 32 + kq) ^ rswz));
    }
    #pragma unroll
    for (int h = 0; h < 2; ++h)
      #pragma unroll
      for (int mi = 0; mi < MI; ++mi)
        #pragma unroll
        for (int ni = 0; ni < NI; ++ni)
          acc[mi][ni] = __builtin_amdgcn_mfma_f32_16x16x32_bf16(af[mi][h], bfr[ni][h], acc[mi][ni], 0, 0, 0);
    __syncthreads();  // drains next-buf stage loads; all cur reads complete
  }
  #undef STAGE

  #pragma unroll
  for (int mi = 0; mi < MI; ++mi) {
    #pragma unroll
    for (int ni = 0; ni < NI; ++ni) {
      int col = colbase + wc * WN + ni * 16 + rrow;
      float bv = BIAS ? bias[col] : 0.f;
      #pragma unroll
      for (int j = 0; j < 4; ++j) {
        int row = rowbase + wr * WM + mi * 16 + (lane >> 4) * 4 + j;
        float v = acc[mi][ni][j] + bv;
        if (RELU) v = fmaxf(v, 0.f);
        C16[(size_t)row * N + col] = f2bf(v);
      }
    }
  }
}

// ---------- output assembly (f32, streaming stores, flag-aware) ----------
__global__ __launch_bounds__(256) void k_assemble(const float* __restrict__ feat,
                                                  const float* __restrict__ logits,
                                                  const int* __restrict__ dx,
                                                  const int* __restrict__ flag,
                                                  float* __restrict__ out) {
  int i = blockIdx.x;  // 0 .. B*7-1
  int b = i / 7, slot = i - b * 7;
  const float* src;
  if (slot <= 1) {
    int f = *flag;
    long p = 7L * b + (slot == 0 ? 1 : 0);  // slot0 -> e2, slot1 -> e1
    int node = dx[f ? 2 * p : p] & (N_NODES - 1);
    src = logits + (size_t)node * DIM;
  } else {
    src = feat + ((size_t)b * 7 + slot) * DIM;
  }
  f32x4 v = *(const f32x4*)(src + threadIdx.x * 4);
  __builtin_nontemporal_store(v, (f32x4*)(out + ((size_t)b * 7 + slot) * DIM + threadIdx.x * 4));
}

extern "C" void kernel_launch(void* const* d_in, const int* in_sizes, int n_in,
                              void* d_out, int out_size, void* d_ws, size_t ws_size,
                              hipStream_t stream) {
  const float* feat   = (const float*)d_in[0];
  const int* data_x   = (const int*)d_in[1];
  const int* adj_rows = (const int*)d_in[2];
  const int* adj_cols = (const int*)d_in[3];
  const float* adj_vals = (const float*)d_in[4];
  const float* W1 = (const float*)d_in[5];
  const float* b1 = (const float*)d_in[6];
  const float* W2 = (const float*)d_in[7];
  const float* b2 = (const float*)d_in[8];
  const float* W3 = (const float*)d_in[9];
  const float* b3 = (const float*)d_in[10];
  float* out = (float*)d_out;

  char* ws = (char*)d_ws;
  size_t off = 0;
  auto alloc = [&](size_t bytes) {
    char* p = ws + off; off += (bytes + 511) & ~(size_t)511; return p;
  };
  int*  flag    = (int*)alloc(4);
  int*  counts  = (int*)alloc(N_NODES * 4);
  int*  bucket  = (int*)alloc((size_t)N_NODES * CAP * 4);
  int*  row_ptr = (int*)alloc((N_NODES + 1) * 4);
  u16*  A1      = (u16*)alloc((size_t)N_NODES * DIM * 2);        // 4 MB
  u16*  S       = (u16*)alloc((size_t)N_NODES * N_NODES * 2);    // 8 MB: S1, S2
  u16*  H       = (u16*)alloc((size_t)N_NODES * N_NODES * 2);    // 8 MB: H1, H2
  u16*  X3      = (u16*)alloc((size_t)N_NODES * DIM * 2);        // 4 MB
  u16*  Wt1     = (u16*)alloc((size_t)DIM * N_NODES * 2);        // 4 MB
  u16*  Wt2     = (u16*)alloc((size_t)N_NODES * N_NODES * 2);    // 8 MB
  u16*  Wt3     = (u16*)alloc((size_t)N_NODES * DIM * 2);        // 4 MB
  float* logits = (float*)alloc((size_t)N_NODES * DIM * 4);      // 8 MB
  // peak ws ~= 46 MB (proven)

  // prep: memset || bucket(inline flag) -> {nodesum | rowptr | transpose3}
  hipMemsetAsync(counts, 0, N_NODES * 4, stream);
  k_bucket<<<(2 * BATCH + 255) / 256, 256, 0, stream>>>(data_x, flag, counts, bucket);
  k_prep2<<<2057 + 8192, 256, 0, stream>>>(feat, counts, bucket, A1, adj_rows, row_ptr,
                                           W1, W2, W3, Wt1, Wt2, Wt3);

  // layer 1: S1 = spmm(A1) [w=1024]; H1 = relu(S1 @ W1 + b1)
  k_spmm<false><<<2048, 256, 0, stream>>>(A1, row_ptr, adj_cols, adj_vals, nullptr, S,
                                          nullptr, DIM);
  k_gemm<128, 128, 512, true, true><<<256, 512, 0, stream>>>(S, Wt1, b1, H, N_NODES, N_NODES, DIM);
  // layer 2: S2 = spmm(H1) [w=2048]; H2 = S2 @ W2 + b2
  k_spmm<false><<<4096, 256, 0, stream>>>(H, row_ptr, adj_cols, adj_vals, nullptr, S,
                                          nullptr, N_NODES);
  k_gemm<128, 128, 512, true, false><<<256, 512, 0, stream>>>(S, Wt2, b2, H, N_NODES, N_NODES, N_NODES);
  // layer 3: X3 = H2 @ W3 ; logits = spmm(X3) + b3 [f32]
  k_gemm<128, 64, 256, false, false><<<256, 256, 0, stream>>>(H, Wt3, nullptr, X3, N_NODES, DIM, N_NODES);
  k_spmm<true><<<2048, 256, 0, stream>>>(X3, row_ptr, adj_cols, adj_vals, b3, nullptr,
                                         logits, DIM);

  // assemble all 7 slots
  k_assemble<<<BATCH * 7, 256, 0, stream>>>(feat, logits, data_x, flag, out);
}